// Round 6
// baseline (1495.754 us; speedup 1.0000x reference)
//
#include <hip/hip_runtime.h>

#define NN 50000
#define NE 800000
#define BN_EPS 1e-5f
#define SCAN_T 256
#define SCAN_NB ((NN + SCAN_T - 1) / SCAN_T) // 196

// stats layout: per-aggregation block of 320 floats; parent at 0, child at 320
#define ST_SUM1 0
#define ST_SQ1 64
#define ST_CROSS 128
#define ST_SUM2 192
#define ST_SSQ2 256
#define ST_AGG 320

#define FILL_B 256
#define FILL_T 1024
#define FILL_R ((NN + FILL_B - 1) / FILL_B) // 196 nodes/block

using bf16x8 = __attribute__((ext_vector_type(8))) __bf16;
using bf16x4 = __attribute__((ext_vector_type(4))) __bf16;
using floatx4 = __attribute__((ext_vector_type(4))) float;

#define MFMA16(a, b, c) __builtin_amdgcn_mfma_f32_16x16x32_bf16(a, b, c, 0, 0, 0)

// W: row-major [K][ncols] f32. B-frag for 16x16x32: lane holds
// B[k = (lane>>4)*8 + j + kb*32][col = ct*16 + (lane&15)], j=0..7.
__device__ __forceinline__ bf16x8 load_wfrag(const float* W, int ncols, int kb, int ct, int lane) {
  int col = ct * 16 + (lane & 15);
  int k0 = kb * 32 + ((lane >> 4) << 3);
  bf16x8 f;
#pragma unroll
  for (int j = 0; j < 8; ++j) f[j] = (__bf16)W[(k0 + j) * ncols + col];
  return f;
}

// ---------------- setup ----------------
__global__ void k_setup(const int* __restrict__ nodes, const float* __restrict__ emb,
                        float* __restrict__ x, int* __restrict__ cnt_d, int* __restrict__ cnt_s) {
  int tid = blockIdx.x * blockDim.x + threadIdx.x;
  int stride = gridDim.x * blockDim.x;
  for (int idx = tid; idx < NN * 64; idx += stride)
    x[idx] = emb[nodes[idx >> 6] * 64 + (idx & 63)];
  for (int n = tid; n < NN; n += stride) { cnt_d[n] = 0; cnt_s[n] = 0; }
}

__global__ void k_hist(const int* __restrict__ src, const int* __restrict__ dst,
                       int* __restrict__ cnt_d, int* __restrict__ cnt_s) {
  int tid = blockIdx.x * blockDim.x + threadIdx.x;
  int stride = gridDim.x * blockDim.x;
  for (int e = tid; e < NE; e += stride) {
    atomicAdd(&cnt_d[dst[e]], 1);
    atomicAdd(&cnt_s[src[e]], 1);
  }
}

__global__ void k_scan1(const int* __restrict__ cnt_d, const int* __restrict__ cnt_s,
                        int* __restrict__ off_d, int* __restrict__ off_s, int* __restrict__ btot) {
  const int* cnt = blockIdx.y ? cnt_s : cnt_d;
  int* off = blockIdx.y ? off_s : off_d;
  __shared__ int sm[SCAN_T];
  int i = blockIdx.x * SCAN_T + threadIdx.x;
  int v = (i < NN) ? cnt[i] : 0;
  sm[threadIdx.x] = v;
  __syncthreads();
  for (int o = 1; o < SCAN_T; o <<= 1) {
    int u = (threadIdx.x >= o) ? sm[threadIdx.x - o] : 0;
    __syncthreads();
    sm[threadIdx.x] += u;
    __syncthreads();
  }
  if (i < NN) off[i] = sm[threadIdx.x]; // in-block inclusive (temp)
  if (threadIdx.x == SCAN_T - 1) btot[blockIdx.y * SCAN_NB + blockIdx.x] = sm[SCAN_T - 1];
}

__global__ void k_scan2(int* __restrict__ btot) {
  __shared__ int sm[SCAN_T];
  int t = threadIdx.x;
  for (int y = 0; y < 2; ++y) {
    int v = (t < SCAN_NB) ? btot[y * SCAN_NB + t] : 0;
    sm[t] = v;
    __syncthreads();
    for (int o = 1; o < SCAN_T; o <<= 1) {
      int u = (t >= o) ? sm[t - o] : 0;
      __syncthreads();
      sm[t] += u;
      __syncthreads();
    }
    if (t < SCAN_NB) btot[y * SCAN_NB + t] = sm[t] - v; // exclusive
    __syncthreads();
  }
}

__global__ void k_scan3(const int* __restrict__ cnt_d, const int* __restrict__ cnt_s,
                        int* __restrict__ off_d, int* __restrict__ off_s,
                        const int* __restrict__ btot, float* __restrict__ dinv_d,
                        float* __restrict__ dinv_s) {
  const int* cnt = blockIdx.y ? cnt_s : cnt_d;
  int* off = blockIdx.y ? off_s : off_d;
  float* dinv = blockIdx.y ? dinv_s : dinv_d;
  int i = blockIdx.x * SCAN_T + threadIdx.x;
  if (i < NN) {
    int incl = off[i];
    int c = cnt[i];
    off[i] = incl - c + btot[blockIdx.y * SCAN_NB + blockIdx.x];
    dinv[i] = c > 0 ? 1.0f / (float)c : 0.f;
  }
  if (i == NN - 1) off[NN] = NE;
}

// Gather-based CSR fill: block owns node range; scans all edges; writes only
// its own contiguous CSR segments. ij_d[p]=(d,s) in dst-CSR; ij_s[p]=(s,d) in
// src-CSR. Block 0 also zeroes the stats buffer (for iteration 0).
__global__ void __launch_bounds__(FILL_T) k_fill_gather(
    const int* __restrict__ src, const int* __restrict__ dst,
    const int* __restrict__ off_d, const int* __restrict__ off_s,
    int2* __restrict__ ij_d, int2* __restrict__ ij_s, float* __restrict__ stats) {
  __shared__ int cur_d[FILL_R], cur_s[FILL_R];
  int n0 = blockIdx.x * FILL_R;
  int n1 = n0 + FILL_R;
  if (n1 > NN) n1 = NN;
  for (int t = threadIdx.x; t < n1 - n0; t += blockDim.x) {
    cur_d[t] = off_d[n0 + t];
    cur_s[t] = off_s[n0 + t];
  }
  __syncthreads();
  const int4* src4 = (const int4*)src;
  const int4* dst4 = (const int4*)dst;
  for (int c = threadIdx.x; c < NE / 4; c += blockDim.x) {
    int4 s4 = src4[c];
    int4 d4 = dst4[c];
    int ss[4] = {s4.x, s4.y, s4.z, s4.w};
    int dd[4] = {d4.x, d4.y, d4.z, d4.w};
#pragma unroll
    for (int k = 0; k < 4; ++k) {
      int s = ss[k], d = dd[k];
      if (d >= n0 && d < n1) {
        int p = atomicAdd(&cur_d[d - n0], 1);
        ij_d[p] = make_int2(d, s);
      }
      if (s >= n0 && s < n1) {
        int p = atomicAdd(&cur_s[s - n0], 1);
        ij_s[p] = make_int2(s, d);
      }
    }
  }
  if (blockIdx.x == 0)
    for (int t = threadIdx.x; t < 2 * ST_AGG; t += blockDim.x) stats[t] = 0.f;
}

// ---------------- per-iteration kernels ----------------
// KA: A = x@W1[0:64]; B = x@W1[64:128] (biases cancel under BN), bf16 out,
// register A-frags. Fused: degree-weighted BN1 node sums (SUM1/SQ1) for its agg.
__global__ void __launch_bounds__(256) k_node_xform(
    const float* __restrict__ x, const float* __restrict__ pW1,
    const float* __restrict__ cW1, __bf16* __restrict__ Ap, __bf16* __restrict__ Bp,
    __bf16* __restrict__ Ac, __bf16* __restrict__ Bc,
    const int* __restrict__ cnt_d, const int* __restrict__ cnt_s,
    float* __restrict__ stats) {
  const int lane = threadIdx.x & 63;
  const int q = lane & 15, g = lane >> 6 ? 0 : (lane >> 4); // g in 0..3
  const int by = blockIdx.y;
  const float* W1 = by ? cW1 : pW1;
  __bf16* Ab = by ? Ac : Ap;
  __bf16* Bb = by ? Bc : Bp;
  bf16x8 wfa[4][2], wfb[4][2];
#pragma unroll
  for (int ct = 0; ct < 4; ++ct)
#pragma unroll
    for (int kb = 0; kb < 2; ++kb) {
      wfa[ct][kb] = load_wfrag(W1, 64, kb, ct, lane);
      wfb[ct][kb] = load_wfrag(W1 + 64 * 64, 64, kb, ct, lane);
    }
  float sumv[4] = {0, 0, 0, 0}, sqv[4] = {0, 0, 0, 0};
  int wgid = (blockIdx.x * blockDim.x + threadIdx.x) >> 6;
  int nw = (gridDim.x * blockDim.x) >> 6;
  for (int tile = wgid; tile < NN / 16; tile += nw) {
    int n = tile * 16 + q;
    const float4* xr0 = (const float4*)(x + (size_t)n * 64 + g * 8);
    const float4* xr1 = (const float4*)(x + (size_t)n * 64 + 32 + g * 8);
    float4 u0 = xr0[0], u1 = xr0[1], w0 = xr1[0], w1 = xr1[1];
    bf16x8 a0, a1;
#pragma unroll
    for (int j = 0; j < 4; ++j) {
      a0[j] = (__bf16)(&u0.x)[j];
      a0[4 + j] = (__bf16)(&u1.x)[j];
      a1[j] = (__bf16)(&w0.x)[j];
      a1[4 + j] = (__bf16)(&w1.x)[j];
    }
    float wAr[4], wBr[4];
#pragma unroll
    for (int r = 0; r < 4; ++r) {
      int nn = tile * 16 + g * 4 + r;
      float wd = (float)cnt_d[nn];
      float ws = (float)cnt_s[nn];
      wAr[r] = by ? ws : wd;
      wBr[r] = by ? wd : ws;
    }
#pragma unroll
    for (int ct = 0; ct < 4; ++ct) {
      floatx4 aA = {0.f, 0.f, 0.f, 0.f}, aB = {0.f, 0.f, 0.f, 0.f};
      aA = MFMA16(a0, wfa[ct][0], aA);
      aA = MFMA16(a1, wfa[ct][1], aA);
      aB = MFMA16(a0, wfb[ct][0], aB);
      aB = MFMA16(a1, wfb[ct][1], aB);
#pragma unroll
      for (int r = 0; r < 4; ++r) {
        int row = g * 4 + r;
        int o = (tile * 16 + row) * 64 + ct * 16 + q;
        Ab[o] = (__bf16)aA[r];
        Bb[o] = (__bf16)aB[r];
        sumv[ct] += wAr[r] * aA[r] + wBr[r] * aB[r];
        sqv[ct] += wAr[r] * aA[r] * aA[r] + wBr[r] * aB[r] * aB[r];
      }
    }
  }
  __shared__ float sacc[128];
  for (int t = threadIdx.x; t < 128; t += blockDim.x) sacc[t] = 0.f;
  __syncthreads();
#pragma unroll
  for (int ct = 0; ct < 4; ++ct) {
    atomicAdd(&sacc[ct * 16 + q], sumv[ct]);
    atomicAdd(&sacc[64 + ct * 16 + q], sqv[ct]);
  }
  __syncthreads();
  int sb = by ? ST_AGG : 0;
  for (int t = threadIdx.x; t < 128; t += blockDim.x)
    atomicAdd(&stats[sb + t], sacc[t]); // SUM1 at 0..63, SQ1 at 64..127
}

// KB: cross terms for BOTH aggs in one p-order pass over the dst-CSR list.
// d monotone -> Ap[d]/Bc[d] stream; only Bp[s]/Ac[s] random.
__global__ void __launch_bounds__(256) k_crossp(
    const int2* __restrict__ ij, const __bf16* __restrict__ Ap,
    const __bf16* __restrict__ Bp, const __bf16* __restrict__ Ac,
    const __bf16* __restrict__ Bc, float* __restrict__ stats) {
  const int lane = threadIdx.x & 63;
  const int q = lane & 15, g = lane >> 4;
  __shared__ float sacc[128];
  for (int t = threadIdx.x; t < 128; t += blockDim.x) sacc[t] = 0.f;
  __syncthreads();
  float cp0[8] = {0}, cp1[8] = {0}, cc0[8] = {0}, cc1[8] = {0};
  int wgid = (blockIdx.x * blockDim.x + threadIdx.x) >> 6;
  int nw = (gridDim.x * blockDim.x) >> 6;
  for (int tile = wgid; tile < NE / 16; tile += nw) {
    int2 e = ij[tile * 16 + q];
    int d = e.x, s = e.y;
    bf16x8 ap0 = *(const bf16x8*)(Ap + (size_t)d * 64 + g * 8);
    bf16x8 ap1 = *(const bf16x8*)(Ap + (size_t)d * 64 + 32 + g * 8);
    bf16x8 bp0 = *(const bf16x8*)(Bp + (size_t)s * 64 + g * 8);
    bf16x8 bp1 = *(const bf16x8*)(Bp + (size_t)s * 64 + 32 + g * 8);
    bf16x8 ac0 = *(const bf16x8*)(Ac + (size_t)s * 64 + g * 8);
    bf16x8 ac1 = *(const bf16x8*)(Ac + (size_t)s * 64 + 32 + g * 8);
    bf16x8 bc0 = *(const bf16x8*)(Bc + (size_t)d * 64 + g * 8);
    bf16x8 bc1 = *(const bf16x8*)(Bc + (size_t)d * 64 + 32 + g * 8);
#pragma unroll
    for (int j = 0; j < 8; ++j) {
      cp0[j] += (float)ap0[j] * (float)bp0[j];
      cp1[j] += (float)ap1[j] * (float)bp1[j];
      cc0[j] += (float)ac0[j] * (float)bc0[j];
      cc1[j] += (float)ac1[j] * (float)bc1[j];
    }
  }
#pragma unroll
  for (int off = 1; off < 16; off <<= 1) {
#pragma unroll
    for (int j = 0; j < 8; ++j) {
      cp0[j] += __shfl_xor(cp0[j], off);
      cp1[j] += __shfl_xor(cp1[j], off);
      cc0[j] += __shfl_xor(cc0[j], off);
      cc1[j] += __shfl_xor(cc1[j], off);
    }
  }
  if (q == 0) {
#pragma unroll
    for (int j = 0; j < 8; ++j) {
      atomicAdd(&sacc[g * 8 + j], cp0[j]);
      atomicAdd(&sacc[32 + g * 8 + j], cp1[j]);
      atomicAdd(&sacc[64 + g * 8 + j], cc0[j]);
      atomicAdd(&sacc[96 + g * 8 + j], cc1[j]);
    }
  }
  __syncthreads();
  for (int t = threadIdx.x; t < 128; t += blockDim.x) {
    int dstoff = (t < 64) ? ST_CROSS + t : ST_AGG + ST_CROSS + (t - 64);
    atomicAdd(&stats[dstoff], sacc[t]);
  }
}

// KC: per-agg edge MLP, p-order over that agg's CSR list (i monotone ->
// A gathers stream). BN1 folded in-register; h2 stored nontemporal at CSR
// position; BN2 stats accumulated.
__global__ void __launch_bounds__(256) k_edge_mlp(
    const int2* __restrict__ ij, const __bf16* __restrict__ A_,
    const __bf16* __restrict__ B_, const float* __restrict__ g1,
    const float* __restrict__ be1, const float* __restrict__ W2,
    float* __restrict__ stats, int sbase, __bf16* __restrict__ h2) {
  const int lane = threadIdx.x & 63;
  const int q = lane & 15, g = lane >> 4;
  float s10[8], t10[8], s11[8], t11[8];
#pragma unroll
  for (int j = 0; j < 8; ++j) {
    int c = g * 8 + j;
    float mu = stats[sbase + ST_SUM1 + c] * (1.f / NE);
    float var = (stats[sbase + ST_SQ1 + c] + 2.f * stats[sbase + ST_CROSS + c]) * (1.f / NE) - mu * mu;
    float s = g1[c] * rsqrtf(var + BN_EPS);
    s10[j] = s;
    t10[j] = be1[c] - mu * s;
    c = 32 + g * 8 + j;
    mu = stats[sbase + ST_SUM1 + c] * (1.f / NE);
    var = (stats[sbase + ST_SQ1 + c] + 2.f * stats[sbase + ST_CROSS + c]) * (1.f / NE) - mu * mu;
    s = g1[c] * rsqrtf(var + BN_EPS);
    s11[j] = s;
    t11[j] = be1[c] - mu * s;
  }
  bf16x8 wf[4][2];
#pragma unroll
  for (int ct = 0; ct < 4; ++ct)
#pragma unroll
    for (int kb = 0; kb < 2; ++kb) wf[ct][kb] = load_wfrag(W2, 64, kb, ct, lane);
  float sum2[4] = {0, 0, 0, 0}, ssq2[4] = {0, 0, 0, 0};
  int wgid = (blockIdx.x * blockDim.x + threadIdx.x) >> 6;
  int nw = (gridDim.x * blockDim.x) >> 6;
  for (int tile = wgid; tile < NE / 16; tile += nw) {
    int p0 = tile * 16;
    int2 e = ij[p0 + q];
    int i = e.x, j2 = e.y;
    bf16x8 a0 = *(const bf16x8*)(A_ + (size_t)i * 64 + g * 8);
    bf16x8 a1 = *(const bf16x8*)(A_ + (size_t)i * 64 + 32 + g * 8);
    bf16x8 b0 = *(const bf16x8*)(B_ + (size_t)j2 * 64 + g * 8);
    bf16x8 b1 = *(const bf16x8*)(B_ + (size_t)j2 * 64 + 32 + g * 8);
    bf16x8 v0, v1;
#pragma unroll
    for (int j = 0; j < 8; ++j) {
      v0[j] = (__bf16)fmaxf(s10[j] * ((float)a0[j] + (float)b0[j]) + t10[j], 0.f);
      v1[j] = (__bf16)fmaxf(s11[j] * ((float)a1[j] + (float)b1[j]) + t11[j], 0.f);
    }
#pragma unroll
    for (int ct = 0; ct < 4; ++ct) {
      floatx4 acc = {0.f, 0.f, 0.f, 0.f};
      acc = MFMA16(v0, wf[ct][0], acc);
      acc = MFMA16(v1, wf[ct][1], acc);
#pragma unroll
      for (int r = 0; r < 4; ++r) {
        float hv = acc[r];
        sum2[ct] += hv;
        ssq2[ct] += hv * hv;
        __bf16 hb = (__bf16)hv;
        short hs = __builtin_bit_cast(short, hb);
        __builtin_nontemporal_store(
            hs, (short*)h2 + (size_t)(p0 + g * 4 + r) * 64 + ct * 16 + q);
      }
    }
  }
  __shared__ float sred[128];
  for (int t = threadIdx.x; t < 128; t += blockDim.x) sred[t] = 0.f;
  __syncthreads();
#pragma unroll
  for (int ct = 0; ct < 4; ++ct) {
    atomicAdd(&sred[ct * 16 + q], sum2[ct]);
    atomicAdd(&sred[64 + ct * 16 + q], ssq2[ct]);
  }
  __syncthreads();
  for (int t = threadIdx.x; t < 128; t += blockDim.x) {
    int dstoff = (t < 64) ? sbase + ST_SUM2 + t : sbase + ST_SSQ2 + (t - 64);
    atomicAdd(&stats[dstoff], sred[t]);
  }
}

// KD: streaming segmented reduction: one wave per node, lane = column.
// relu(bn2(h2)) summed over the node's contiguous CSR range, degree-normalized.
__global__ void __launch_bounds__(256) k_scatter(
    const int* __restrict__ off, const float* __restrict__ dinv,
    const float* __restrict__ g2, const float* __restrict__ be2,
    const float* __restrict__ stats, int sbase, const __bf16* __restrict__ h2,
    __bf16* __restrict__ outb) {
  const int lane = threadIdx.x & 63;
  float mu = stats[sbase + ST_SUM2 + lane] * (1.f / NE);
  float var = stats[sbase + ST_SSQ2 + lane] * (1.f / NE) - mu * mu;
  float s2 = g2[lane] * rsqrtf(var + BN_EPS);
  float t2 = be2[lane] - mu * s2;
  int wgid = (blockIdx.x * blockDim.x + threadIdx.x) >> 6;
  int nw = (gridDim.x * blockDim.x) >> 6;
  for (int n = wgid; n < NN; n += nw) {
    int p0 = off[n], p1 = off[n + 1];
    float acc = 0.f;
    for (int p = p0; p < p1; ++p) {
      short hs = __builtin_nontemporal_load((const short*)h2 + (size_t)p * 64 + lane);
      float h = __uint_as_float(((unsigned)(unsigned short)hs) << 16);
      acc += fmaxf(s2 * h + t2, 0.f);
    }
    outb[(size_t)n * 64 + lane] = (__bf16)(dinv[n] * acc);
  }
}

// KE: fused node update: upd = relu([x|fi|fo]@fcW + fcb)@fc2W + fc2b ; x += upd.
// Block 0 zeroes stats for the NEXT iteration (no stats reader runs after this
// kernel within an iteration).
__global__ void __launch_bounds__(256) k_node_update(
    float* __restrict__ x, const __bf16* __restrict__ fi, const __bf16* __restrict__ fo,
    const float* __restrict__ fcW, const float* __restrict__ fcb,
    const float* __restrict__ fc2W, const float* __restrict__ fc2b,
    float* __restrict__ stats) {
  const int lane = threadIdx.x & 63;
  const int wid = threadIdx.x >> 6;
  const int q = lane & 15, g = lane >> 4;
  __shared__ alignas(16) __bf16 v2[16 * 136];
  bf16x8 wf1[2][6];
#pragma unroll
  for (int c = 0; c < 2; ++c) {
    int ct = 2 * wid + c;
#pragma unroll
    for (int kb = 0; kb < 6; ++kb) wf1[c][kb] = load_wfrag(fcW, 128, kb, ct, lane);
  }
  bf16x8 wf2[4];
#pragma unroll
  for (int kb = 0; kb < 4; ++kb) wf2[kb] = load_wfrag(fc2W, 64, kb, wid, lane);
  float fcbv[2];
#pragma unroll
  for (int c = 0; c < 2; ++c) fcbv[c] = fcb[(2 * wid + c) * 16 + q];
  float fc2bv = fc2b[wid * 16 + q];

  for (int tile = blockIdx.x; tile < NN / 16; tile += gridDim.x) {
    int n = tile * 16 + q;
    const float4* xr0 = (const float4*)(x + (size_t)n * 64 + g * 8);
    const float4* xr1 = (const float4*)(x + (size_t)n * 64 + 32 + g * 8);
    float4 u0 = xr0[0], u1 = xr0[1], w0 = xr1[0], w1 = xr1[1];
    bf16x8 af[6];
#pragma unroll
    for (int j = 0; j < 4; ++j) {
      af[0][j] = (__bf16)(&u0.x)[j];
      af[0][4 + j] = (__bf16)(&u1.x)[j];
      af[1][j] = (__bf16)(&w0.x)[j];
      af[1][4 + j] = (__bf16)(&w1.x)[j];
    }
    af[2] = *(const bf16x8*)(fi + (size_t)n * 64 + g * 8);
    af[3] = *(const bf16x8*)(fi + (size_t)n * 64 + 32 + g * 8);
    af[4] = *(const bf16x8*)(fo + (size_t)n * 64 + g * 8);
    af[5] = *(const bf16x8*)(fo + (size_t)n * 64 + 32 + g * 8);
    floatx4 acc0 = {0.f, 0.f, 0.f, 0.f}, acc1 = {0.f, 0.f, 0.f, 0.f};
#pragma unroll
    for (int kb = 0; kb < 6; ++kb) {
      acc0 = MFMA16(af[kb], wf1[0][kb], acc0);
      acc1 = MFMA16(af[kb], wf1[1][kb], acc1);
    }
#pragma unroll
    for (int r = 0; r < 4; ++r) {
      int row = g * 4 + r;
      v2[row * 136 + (2 * wid) * 16 + q] = (__bf16)fmaxf(acc0[r] + fcbv[0], 0.f);
      v2[row * 136 + (2 * wid + 1) * 16 + q] = (__bf16)fmaxf(acc1[r] + fcbv[1], 0.f);
    }
    __syncthreads();
    floatx4 a2 = {0.f, 0.f, 0.f, 0.f};
#pragma unroll
    for (int kb = 0; kb < 4; ++kb) {
      bf16x8 af2 = *(const bf16x8*)&v2[q * 136 + kb * 32 + g * 8];
      a2 = MFMA16(af2, wf2[kb], a2);
    }
#pragma unroll
    for (int r = 0; r < 4; ++r) {
      int row = g * 4 + r;
      x[(size_t)(tile * 16 + row) * 64 + wid * 16 + q] += a2[r] + fc2bv;
    }
    __syncthreads();
  }
  if (blockIdx.x == 0)
    for (int t = threadIdx.x; t < 2 * ST_AGG; t += blockDim.x) stats[t] = 0.f;
}

// KF: out = x@convW + convb (f32 for accuracy margin).
__global__ void __launch_bounds__(256) k_conv(const float* __restrict__ x,
                                              const float* __restrict__ convW,
                                              const float* __restrict__ convb,
                                              float* __restrict__ out) {
  const int lane = threadIdx.x & 63;
  int wgid = (blockIdx.x * blockDim.x + threadIdx.x) >> 6;
  int nw = (gridDim.x * blockDim.x) >> 6;
  int half = wgid & 1;
  int col = half * 64 + lane;
  float wreg[64];
#pragma unroll
  for (int k = 0; k < 64; ++k) wreg[k] = convW[k * 128 + col];
  float bv = convb[col];
  for (int n = (wgid >> 1); n < NN; n += (nw >> 1)) {
    float xv = x[n * 64 + lane];
    float acc = bv;
#pragma unroll
    for (int k = 0; k < 64; ++k) acc += __shfl(xv, k) * wreg[k];
    out[(size_t)n * 128 + col] = acc;
  }
}

extern "C" void kernel_launch(void* const* d_in, const int* in_sizes, int n_in,
                              void* d_out, int out_size, void* d_ws, size_t ws_size,
                              hipStream_t stream) {
  const int* nodes = (const int*)d_in[0];
  const int* edges = (const int*)d_in[1];
  const int* src = edges;      // edges[0]
  const int* dst = edges + NE; // edges[1]
  const float* emb = (const float*)d_in[2];
  const float* pW1 = (const float*)d_in[3];
  const float* pg1 = (const float*)d_in[5];
  const float* pbe1 = (const float*)d_in[6];
  const float* pW2 = (const float*)d_in[7];
  const float* pg2 = (const float*)d_in[9];
  const float* pbe2 = (const float*)d_in[10];
  const float* cW1 = (const float*)d_in[11];
  const float* cg1 = (const float*)d_in[13];
  const float* cbe1 = (const float*)d_in[14];
  const float* cW2 = (const float*)d_in[15];
  const float* cg2 = (const float*)d_in[17];
  const float* cbe2 = (const float*)d_in[18];
  const float* fcW = (const float*)d_in[19];
  const float* fcb = (const float*)d_in[20];
  const float* fc2W = (const float*)d_in[21];
  const float* fc2b = (const float*)d_in[22];
  const float* convW = (const float*)d_in[23];
  const float* convb = (const float*)d_in[24];
  float* out = (float*)d_out;

  char* w = (char*)d_ws;
  auto alloc = [&](size_t bytes) {
    char* p = w;
    w += (bytes + 255) & ~(size_t)255;
    return p;
  };
  float* x = (float*)alloc((size_t)NN * 64 * 4);
  __bf16* Ap = (__bf16*)alloc((size_t)NN * 64 * 2);
  __bf16* Bp = (__bf16*)alloc((size_t)NN * 64 * 2);
  __bf16* Ac = (__bf16*)alloc((size_t)NN * 64 * 2);
  __bf16* Bc = (__bf16*)alloc((size_t)NN * 64 * 2);
  __bf16* fi = (__bf16*)alloc((size_t)NN * 64 * 2);
  __bf16* fo = (__bf16*)alloc((size_t)NN * 64 * 2);
  __bf16* h2 = (__bf16*)alloc((size_t)NE * 64 * 2); // shared by parent/child
  int2* ij_d = (int2*)alloc((size_t)NE * 8);
  int2* ij_s = (int2*)alloc((size_t)NE * 8);
  int* off_d = (int*)alloc((size_t)(NN + 1) * 4);
  int* off_s = (int*)alloc((size_t)(NN + 1) * 4);
  int* cnt_d = (int*)alloc((size_t)NN * 4);
  int* cnt_s = (int*)alloc((size_t)NN * 4);
  float* dinv_d = (float*)alloc((size_t)NN * 4);
  float* dinv_s = (float*)alloc((size_t)NN * 4);
  float* stats = (float*)alloc(2 * ST_AGG * 4);
  int* btot = (int*)alloc(2 * SCAN_NB * 4);

  k_setup<<<1024, 256, 0, stream>>>(nodes, emb, x, cnt_d, cnt_s);
  k_hist<<<1024, 256, 0, stream>>>(src, dst, cnt_d, cnt_s);
  k_scan1<<<dim3(SCAN_NB, 2), SCAN_T, 0, stream>>>(cnt_d, cnt_s, off_d, off_s, btot);
  k_scan2<<<1, SCAN_T, 0, stream>>>(btot);
  k_scan3<<<dim3(SCAN_NB, 2), SCAN_T, 0, stream>>>(cnt_d, cnt_s, off_d, off_s, btot,
                                                   dinv_d, dinv_s);
  k_fill_gather<<<FILL_B, FILL_T, 0, stream>>>(src, dst, off_d, off_s, ij_d, ij_s, stats);

  for (int it = 0; it < 2; ++it) {
    k_node_xform<<<dim3(784, 2), 256, 0, stream>>>(x, pW1, cW1, Ap, Bp, Ac, Bc,
                                                   cnt_d, cnt_s, stats);
    k_crossp<<<2048, 256, 0, stream>>>(ij_d, Ap, Bp, Ac, Bc, stats);
    // Parent: i = dst (monotone in ij_d), j = src
    k_edge_mlp<<<4096, 256, 0, stream>>>(ij_d, Ap, Bp, pg1, pbe1, pW2, stats, 0, h2);
    k_scatter<<<2048, 256, 0, stream>>>(off_d, dinv_d, pg2, pbe2, stats, 0, h2, fi);
    // Child: i = src (monotone in ij_s), j = dst
    k_edge_mlp<<<4096, 256, 0, stream>>>(ij_s, Ac, Bc, cg1, cbe1, cW2, stats, ST_AGG, h2);
    k_scatter<<<2048, 256, 0, stream>>>(off_s, dinv_s, cg2, cbe2, stats, ST_AGG, h2, fo);
    // Node update (+ stats zero for next iteration)
    k_node_update<<<3125, 256, 0, stream>>>(x, fi, fo, fcW, fcb, fc2W, fc2b, stats);
  }
  k_conv<<<2048, 256, 0, stream>>>(x, convW, convb, out);
}

// Round 7
// 1230.478 us; speedup vs baseline: 1.2156x; 1.2156x over previous
//
#include <hip/hip_runtime.h>

#define NN 50000
#define NE 800000
#define BN_EPS 1e-5f
#define SCAN_T 256
#define SCAN_NB ((NN + SCAN_T - 1) / SCAN_T) // 196

// stats layout: per-aggregation block of 320 floats; parent at 0, child at 320
#define ST_SUM1 0
#define ST_SQ1 64
#define ST_CROSS 128
#define ST_SUM2 192
#define ST_SSQ2 256
#define ST_AGG 320

#define FILL_B 256
#define FILL_T 1024
#define FILL_R ((NN + FILL_B - 1) / FILL_B) // 196 nodes/block

using bf16x8 = __attribute__((ext_vector_type(8))) __bf16;
using bf16x4 = __attribute__((ext_vector_type(4))) __bf16;
using floatx4 = __attribute__((ext_vector_type(4))) float;

#define MFMA16(a, b, c) __builtin_amdgcn_mfma_f32_16x16x32_bf16(a, b, c, 0, 0, 0)

// W: row-major [K][ncols] f32. B-frag for 16x16x32: lane holds
// B[k = (lane>>4)*8 + j + kb*32][col = ct*16 + (lane&15)], j=0..7.
__device__ __forceinline__ bf16x8 load_wfrag(const float* W, int ncols, int kb, int ct, int lane) {
  int col = ct * 16 + (lane & 15);
  int k0 = kb * 32 + ((lane >> 4) << 3);
  bf16x8 f;
#pragma unroll
  for (int j = 0; j < 8; ++j) f[j] = (__bf16)W[(k0 + j) * ncols + col];
  return f;
}

// ---------------- setup ----------------
__global__ void k_setup(const int* __restrict__ nodes, const float* __restrict__ emb,
                        float* __restrict__ x, int* __restrict__ cnt_d, int* __restrict__ cnt_s) {
  int tid = blockIdx.x * blockDim.x + threadIdx.x;
  int stride = gridDim.x * blockDim.x;
  for (int idx = tid; idx < NN * 64; idx += stride)
    x[idx] = emb[nodes[idx >> 6] * 64 + (idx & 63)];
  for (int n = tid; n < NN; n += stride) { cnt_d[n] = 0; cnt_s[n] = 0; }
}

__global__ void k_hist(const int* __restrict__ src, const int* __restrict__ dst,
                       int* __restrict__ cnt_d, int* __restrict__ cnt_s) {
  int tid = blockIdx.x * blockDim.x + threadIdx.x;
  int stride = gridDim.x * blockDim.x;
  for (int e = tid; e < NE; e += stride) {
    atomicAdd(&cnt_d[dst[e]], 1);
    atomicAdd(&cnt_s[src[e]], 1);
  }
}

__global__ void k_scan1(const int* __restrict__ cnt_d, const int* __restrict__ cnt_s,
                        int* __restrict__ off_d, int* __restrict__ off_s, int* __restrict__ btot) {
  const int* cnt = blockIdx.y ? cnt_s : cnt_d;
  int* off = blockIdx.y ? off_s : off_d;
  __shared__ int sm[SCAN_T];
  int i = blockIdx.x * SCAN_T + threadIdx.x;
  int v = (i < NN) ? cnt[i] : 0;
  sm[threadIdx.x] = v;
  __syncthreads();
  for (int o = 1; o < SCAN_T; o <<= 1) {
    int u = (threadIdx.x >= o) ? sm[threadIdx.x - o] : 0;
    __syncthreads();
    sm[threadIdx.x] += u;
    __syncthreads();
  }
  if (i < NN) off[i] = sm[threadIdx.x]; // in-block inclusive (temp)
  if (threadIdx.x == SCAN_T - 1) btot[blockIdx.y * SCAN_NB + blockIdx.x] = sm[SCAN_T - 1];
}

__global__ void k_scan2(int* __restrict__ btot) {
  __shared__ int sm[SCAN_T];
  int t = threadIdx.x;
  for (int y = 0; y < 2; ++y) {
    int v = (t < SCAN_NB) ? btot[y * SCAN_NB + t] : 0;
    sm[t] = v;
    __syncthreads();
    for (int o = 1; o < SCAN_T; o <<= 1) {
      int u = (t >= o) ? sm[t - o] : 0;
      __syncthreads();
      sm[t] += u;
      __syncthreads();
    }
    if (t < SCAN_NB) btot[y * SCAN_NB + t] = sm[t] - v; // exclusive
    __syncthreads();
  }
}

__global__ void k_scan3(const int* __restrict__ cnt_d, const int* __restrict__ cnt_s,
                        int* __restrict__ off_d, int* __restrict__ off_s,
                        const int* __restrict__ btot, float* __restrict__ dinv_d,
                        float* __restrict__ dinv_s) {
  const int* cnt = blockIdx.y ? cnt_s : cnt_d;
  int* off = blockIdx.y ? off_s : off_d;
  float* dinv = blockIdx.y ? dinv_s : dinv_d;
  int i = blockIdx.x * SCAN_T + threadIdx.x;
  if (i < NN) {
    int incl = off[i];
    int c = cnt[i];
    off[i] = incl - c + btot[blockIdx.y * SCAN_NB + blockIdx.x];
    dinv[i] = c > 0 ? 1.0f / (float)c : 0.f;
  }
  if (i == NN - 1) off[NN] = NE;
}

// Gather-based CSR fill: block owns node range; scans all edges; writes only
// its own contiguous CSR segments. ij_d[p]=(d,s) in dst-CSR; ij_s[p]=(s,d) in
// src-CSR. Block 0 also zeroes the stats buffer (for iteration 0).
__global__ void __launch_bounds__(FILL_T) k_fill_gather(
    const int* __restrict__ src, const int* __restrict__ dst,
    const int* __restrict__ off_d, const int* __restrict__ off_s,
    int2* __restrict__ ij_d, int2* __restrict__ ij_s, float* __restrict__ stats) {
  __shared__ int cur_d[FILL_R], cur_s[FILL_R];
  int n0 = blockIdx.x * FILL_R;
  int n1 = n0 + FILL_R;
  if (n1 > NN) n1 = NN;
  for (int t = threadIdx.x; t < n1 - n0; t += blockDim.x) {
    cur_d[t] = off_d[n0 + t];
    cur_s[t] = off_s[n0 + t];
  }
  __syncthreads();
  const int4* src4 = (const int4*)src;
  const int4* dst4 = (const int4*)dst;
  for (int c = threadIdx.x; c < NE / 4; c += blockDim.x) {
    int4 s4 = src4[c];
    int4 d4 = dst4[c];
    int ss[4] = {s4.x, s4.y, s4.z, s4.w};
    int dd[4] = {d4.x, d4.y, d4.z, d4.w};
#pragma unroll
    for (int k = 0; k < 4; ++k) {
      int s = ss[k], d = dd[k];
      if (d >= n0 && d < n1) {
        int p = atomicAdd(&cur_d[d - n0], 1);
        ij_d[p] = make_int2(d, s);
      }
      if (s >= n0 && s < n1) {
        int p = atomicAdd(&cur_s[s - n0], 1);
        ij_s[p] = make_int2(s, d);
      }
    }
  }
  if (blockIdx.x == 0)
    for (int t = threadIdx.x; t < 2 * ST_AGG; t += blockDim.x) stats[t] = 0.f;
}

// ---------------- per-iteration kernels ----------------
// KA: A = x@W1[0:64]; B = x@W1[64:128] (biases cancel under BN), bf16 out,
// register A-frags. Fused: degree-weighted BN1 node sums (SUM1/SQ1) for its agg.
__global__ void __launch_bounds__(256) k_node_xform(
    const float* __restrict__ x, const float* __restrict__ pW1,
    const float* __restrict__ cW1, __bf16* __restrict__ Ap, __bf16* __restrict__ Bp,
    __bf16* __restrict__ Ac, __bf16* __restrict__ Bc,
    const int* __restrict__ cnt_d, const int* __restrict__ cnt_s,
    float* __restrict__ stats) {
  const int lane = threadIdx.x & 63;
  const int q = lane & 15, g = lane >> 4;
  const int by = blockIdx.y;
  const float* W1 = by ? cW1 : pW1;
  __bf16* Ab = by ? Ac : Ap;
  __bf16* Bb = by ? Bc : Bp;
  bf16x8 wfa[4][2], wfb[4][2];
#pragma unroll
  for (int ct = 0; ct < 4; ++ct)
#pragma unroll
    for (int kb = 0; kb < 2; ++kb) {
      wfa[ct][kb] = load_wfrag(W1, 64, kb, ct, lane);
      wfb[ct][kb] = load_wfrag(W1 + 64 * 64, 64, kb, ct, lane);
    }
  float sumv[4] = {0, 0, 0, 0}, sqv[4] = {0, 0, 0, 0};
  int wgid = (blockIdx.x * blockDim.x + threadIdx.x) >> 6;
  int nw = (gridDim.x * blockDim.x) >> 6;
  for (int tile = wgid; tile < NN / 16; tile += nw) {
    int n = tile * 16 + q;
    const float4* xr0 = (const float4*)(x + (size_t)n * 64 + g * 8);
    const float4* xr1 = (const float4*)(x + (size_t)n * 64 + 32 + g * 8);
    float4 u0 = xr0[0], u1 = xr0[1], w0 = xr1[0], w1 = xr1[1];
    bf16x8 a0, a1;
#pragma unroll
    for (int j = 0; j < 4; ++j) {
      a0[j] = (__bf16)(&u0.x)[j];
      a0[4 + j] = (__bf16)(&u1.x)[j];
      a1[j] = (__bf16)(&w0.x)[j];
      a1[4 + j] = (__bf16)(&w1.x)[j];
    }
    float wAr[4], wBr[4];
#pragma unroll
    for (int r = 0; r < 4; ++r) {
      int nn = tile * 16 + g * 4 + r;
      float wd = (float)cnt_d[nn];
      float ws = (float)cnt_s[nn];
      wAr[r] = by ? ws : wd;
      wBr[r] = by ? wd : ws;
    }
#pragma unroll
    for (int ct = 0; ct < 4; ++ct) {
      floatx4 aA = {0.f, 0.f, 0.f, 0.f}, aB = {0.f, 0.f, 0.f, 0.f};
      aA = MFMA16(a0, wfa[ct][0], aA);
      aA = MFMA16(a1, wfa[ct][1], aA);
      aB = MFMA16(a0, wfb[ct][0], aB);
      aB = MFMA16(a1, wfb[ct][1], aB);
#pragma unroll
      for (int r = 0; r < 4; ++r) {
        int row = g * 4 + r;
        int o = (tile * 16 + row) * 64 + ct * 16 + q;
        Ab[o] = (__bf16)aA[r];
        Bb[o] = (__bf16)aB[r];
        sumv[ct] += wAr[r] * aA[r] + wBr[r] * aB[r];
        sqv[ct] += wAr[r] * aA[r] * aA[r] + wBr[r] * aB[r] * aB[r];
      }
    }
  }
  __shared__ float sacc[128];
  for (int t = threadIdx.x; t < 128; t += blockDim.x) sacc[t] = 0.f;
  __syncthreads();
#pragma unroll
  for (int ct = 0; ct < 4; ++ct) {
    atomicAdd(&sacc[ct * 16 + q], sumv[ct]);
    atomicAdd(&sacc[64 + ct * 16 + q], sqv[ct]);
  }
  __syncthreads();
  int sb = by ? ST_AGG : 0;
  for (int t = threadIdx.x; t < 128; t += blockDim.x)
    atomicAdd(&stats[sb + t], sacc[t]); // SUM1 at 0..63, SQ1 at 64..127
}

// KB: cross terms for BOTH aggs in one p-order pass over the dst-CSR list.
// d monotone -> Ap[d]/Bc[d] stream; only Bp[s]/Ac[s] random.
__global__ void __launch_bounds__(256) k_crossp(
    const int2* __restrict__ ij, const __bf16* __restrict__ Ap,
    const __bf16* __restrict__ Bp, const __bf16* __restrict__ Ac,
    const __bf16* __restrict__ Bc, float* __restrict__ stats) {
  const int lane = threadIdx.x & 63;
  const int q = lane & 15, g = lane >> 4;
  __shared__ float sacc[128];
  for (int t = threadIdx.x; t < 128; t += blockDim.x) sacc[t] = 0.f;
  __syncthreads();
  float cp0[8] = {0}, cp1[8] = {0}, cc0[8] = {0}, cc1[8] = {0};
  int wgid = (blockIdx.x * blockDim.x + threadIdx.x) >> 6;
  int nw = (gridDim.x * blockDim.x) >> 6;
  for (int tile = wgid; tile < NE / 16; tile += nw) {
    int2 e = ij[tile * 16 + q];
    int d = e.x, s = e.y;
    bf16x8 ap0 = *(const bf16x8*)(Ap + (size_t)d * 64 + g * 8);
    bf16x8 ap1 = *(const bf16x8*)(Ap + (size_t)d * 64 + 32 + g * 8);
    bf16x8 bp0 = *(const bf16x8*)(Bp + (size_t)s * 64 + g * 8);
    bf16x8 bp1 = *(const bf16x8*)(Bp + (size_t)s * 64 + 32 + g * 8);
    bf16x8 ac0 = *(const bf16x8*)(Ac + (size_t)s * 64 + g * 8);
    bf16x8 ac1 = *(const bf16x8*)(Ac + (size_t)s * 64 + 32 + g * 8);
    bf16x8 bc0 = *(const bf16x8*)(Bc + (size_t)d * 64 + g * 8);
    bf16x8 bc1 = *(const bf16x8*)(Bc + (size_t)d * 64 + 32 + g * 8);
#pragma unroll
    for (int j = 0; j < 8; ++j) {
      cp0[j] += (float)ap0[j] * (float)bp0[j];
      cp1[j] += (float)ap1[j] * (float)bp1[j];
      cc0[j] += (float)ac0[j] * (float)bc0[j];
      cc1[j] += (float)ac1[j] * (float)bc1[j];
    }
  }
#pragma unroll
  for (int off = 1; off < 16; off <<= 1) {
#pragma unroll
    for (int j = 0; j < 8; ++j) {
      cp0[j] += __shfl_xor(cp0[j], off);
      cp1[j] += __shfl_xor(cp1[j], off);
      cc0[j] += __shfl_xor(cc0[j], off);
      cc1[j] += __shfl_xor(cc1[j], off);
    }
  }
  if (q == 0) {
#pragma unroll
    for (int j = 0; j < 8; ++j) {
      atomicAdd(&sacc[g * 8 + j], cp0[j]);
      atomicAdd(&sacc[32 + g * 8 + j], cp1[j]);
      atomicAdd(&sacc[64 + g * 8 + j], cc0[j]);
      atomicAdd(&sacc[96 + g * 8 + j], cc1[j]);
    }
  }
  __syncthreads();
  for (int t = threadIdx.x; t < 128; t += blockDim.x) {
    int dstoff = (t < 64) ? ST_CROSS + t : ST_AGG + ST_CROSS + (t - 64);
    atomicAdd(&stats[dstoff], sacc[t]);
  }
}

// KC: prescale by BN1: A' = s1*A + t1, B' = s1*B (in-place, both aggs).
__global__ void __launch_bounds__(256) k_prescale(
    __bf16* __restrict__ Ap, __bf16* __restrict__ Bp,
    __bf16* __restrict__ Ac, __bf16* __restrict__ Bc,
    const float* __restrict__ pg1, const float* __restrict__ pbe1,
    const float* __restrict__ cg1, const float* __restrict__ cbe1,
    const float* __restrict__ stats) {
  int tid = blockIdx.x * blockDim.x + threadIdx.x;
  int nthreads = gridDim.x * blockDim.x;
  int c4 = (tid & 15) * 4;
  float s1p[4], t1p[4], s1c[4], t1c[4];
#pragma unroll
  for (int k = 0; k < 4; ++k) {
    int c = c4 + k;
    float mu = stats[ST_SUM1 + c] * (1.f / NE);
    float var = (stats[ST_SQ1 + c] + 2.f * stats[ST_CROSS + c]) * (1.f / NE) - mu * mu;
    float s = pg1[c] * rsqrtf(var + BN_EPS);
    s1p[k] = s;
    t1p[k] = pbe1[c] - mu * s;
    mu = stats[ST_AGG + ST_SUM1 + c] * (1.f / NE);
    var = (stats[ST_AGG + ST_SQ1 + c] + 2.f * stats[ST_AGG + ST_CROSS + c]) * (1.f / NE) - mu * mu;
    s = cg1[c] * rsqrtf(var + BN_EPS);
    s1c[k] = s;
    t1c[k] = cbe1[c] - mu * s;
  }
  for (int n = tid >> 4; n < NN; n += nthreads >> 4) {
    size_t o = (size_t)n * 64 + c4;
    bf16x4 ap = *(bf16x4*)(Ap + o), bp = *(bf16x4*)(Bp + o);
    bf16x4 ac = *(bf16x4*)(Ac + o), bc = *(bf16x4*)(Bc + o);
#pragma unroll
    for (int k = 0; k < 4; ++k) {
      ap[k] = (__bf16)(s1p[k] * (float)ap[k] + t1p[k]);
      bp[k] = (__bf16)(s1p[k] * (float)bp[k]);
      ac[k] = (__bf16)(s1c[k] * (float)ac[k] + t1c[k]);
      bc[k] = (__bf16)(s1c[k] * (float)bc[k]);
    }
    *(bf16x4*)(Ap + o) = ap;
    *(bf16x4*)(Bp + o) = bp;
    *(bf16x4*)(Ac + o) = ac;
    *(bf16x4*)(Bc + o) = bc;
  }
}

// KD: BN2 stats for BOTH aggs in one p-order pass (no h2 store). i=d monotone
// -> Ap[d]/Bc[d] stream; Bp[s]/Ac[s] random. v=relu(A'+B'); h2=v@W2.
__global__ void __launch_bounds__(256) k_bn2p(
    const int2* __restrict__ ij, const __bf16* __restrict__ Ap,
    const __bf16* __restrict__ Bp, const __bf16* __restrict__ Ac,
    const __bf16* __restrict__ Bc, const float* __restrict__ pW2,
    const float* __restrict__ cW2, float* __restrict__ stats) {
  const int lane = threadIdx.x & 63;
  const int q = lane & 15, g = lane >> 4;
  __shared__ float sred[256];
  for (int t = threadIdx.x; t < 256; t += blockDim.x) sred[t] = 0.f;
  __syncthreads();
  bf16x8 wfp[4][2], wfc[4][2];
#pragma unroll
  for (int ct = 0; ct < 4; ++ct)
#pragma unroll
    for (int kb = 0; kb < 2; ++kb) {
      wfp[ct][kb] = load_wfrag(pW2, 64, kb, ct, lane);
      wfc[ct][kb] = load_wfrag(cW2, 64, kb, ct, lane);
    }
  float sump[4] = {0, 0, 0, 0}, ssqp[4] = {0, 0, 0, 0};
  float sumc[4] = {0, 0, 0, 0}, ssqc[4] = {0, 0, 0, 0};
  int wgid = (blockIdx.x * blockDim.x + threadIdx.x) >> 6;
  int nw = (gridDim.x * blockDim.x) >> 6;
  for (int tile = wgid; tile < NE / 16; tile += nw) {
    int2 e = ij[tile * 16 + q];
    int d = e.x, s = e.y;
    bf16x8 ap0 = *(const bf16x8*)(Ap + (size_t)d * 64 + g * 8);
    bf16x8 ap1 = *(const bf16x8*)(Ap + (size_t)d * 64 + 32 + g * 8);
    bf16x8 bp0 = *(const bf16x8*)(Bp + (size_t)s * 64 + g * 8);
    bf16x8 bp1 = *(const bf16x8*)(Bp + (size_t)s * 64 + 32 + g * 8);
    bf16x8 ac0 = *(const bf16x8*)(Ac + (size_t)s * 64 + g * 8);
    bf16x8 ac1 = *(const bf16x8*)(Ac + (size_t)s * 64 + 32 + g * 8);
    bf16x8 bc0 = *(const bf16x8*)(Bc + (size_t)d * 64 + g * 8);
    bf16x8 bc1 = *(const bf16x8*)(Bc + (size_t)d * 64 + 32 + g * 8);
    bf16x8 vp0, vp1, vc0, vc1;
#pragma unroll
    for (int j = 0; j < 8; ++j) {
      vp0[j] = (__bf16)fmaxf((float)ap0[j] + (float)bp0[j], 0.f);
      vp1[j] = (__bf16)fmaxf((float)ap1[j] + (float)bp1[j], 0.f);
      vc0[j] = (__bf16)fmaxf((float)ac0[j] + (float)bc0[j], 0.f);
      vc1[j] = (__bf16)fmaxf((float)ac1[j] + (float)bc1[j], 0.f);
    }
#pragma unroll
    for (int ct = 0; ct < 4; ++ct) {
      floatx4 accp = {0.f, 0.f, 0.f, 0.f}, accc = {0.f, 0.f, 0.f, 0.f};
      accp = MFMA16(vp0, wfp[ct][0], accp);
      accp = MFMA16(vp1, wfp[ct][1], accp);
      accc = MFMA16(vc0, wfc[ct][0], accc);
      accc = MFMA16(vc1, wfc[ct][1], accc);
#pragma unroll
      for (int r = 0; r < 4; ++r) {
        float hp = accp[r], hc = accc[r];
        sump[ct] += hp;
        ssqp[ct] += hp * hp;
        sumc[ct] += hc;
        ssqc[ct] += hc * hc;
      }
    }
  }
#pragma unroll
  for (int ct = 0; ct < 4; ++ct) {
    atomicAdd(&sred[ct * 16 + q], sump[ct]);
    atomicAdd(&sred[64 + ct * 16 + q], ssqp[ct]);
    atomicAdd(&sred[128 + ct * 16 + q], sumc[ct]);
    atomicAdd(&sred[192 + ct * 16 + q], ssqc[ct]);
  }
  __syncthreads();
  for (int t = threadIdx.x; t < 256; t += blockDim.x) {
    int dstoff;
    if (t < 64) dstoff = ST_SUM2 + t;
    else if (t < 128) dstoff = ST_SSQ2 + (t - 64);
    else if (t < 192) dstoff = ST_AGG + ST_SUM2 + (t - 128);
    else dstoff = ST_AGG + ST_SSQ2 + (t - 192);
    atomicAdd(&stats[dstoff], sred[t]);
  }
}

// KE: fused edge-MLP + segmented scatter, both aggs (wave split), register
// A-frags, per-node CSR walk (A-row amortized; only B[j] random), bf16 output.
__global__ void __launch_bounds__(256) k_scatter_both(
    const int* __restrict__ off_d, const float* __restrict__ dinv_d,
    const int2* __restrict__ ij_d, const int* __restrict__ off_s,
    const float* __restrict__ dinv_s, const int2* __restrict__ ij_s,
    const __bf16* __restrict__ Ap, const __bf16* __restrict__ Bp,
    const __bf16* __restrict__ Ac, const __bf16* __restrict__ Bc,
    const float* __restrict__ pg2, const float* __restrict__ pbe2,
    const float* __restrict__ cg2, const float* __restrict__ cbe2,
    const float* __restrict__ pW2, const float* __restrict__ cW2,
    const float* __restrict__ stats, __bf16* __restrict__ fi,
    __bf16* __restrict__ fo) {
  const int lane = threadIdx.x & 63;
  const int q = lane & 15, g = lane >> 4;
  int wgid = (blockIdx.x * blockDim.x + threadIdx.x) >> 6;
  int nw = (gridDim.x * blockDim.x) >> 6;
  int half = nw >> 1;
  bool child = wgid >= half;
  const int* off = child ? off_s : off_d;
  const float* dinv = child ? dinv_s : dinv_d;
  const int2* ij = child ? ij_s : ij_d;
  const __bf16* A_ = child ? Ac : Ap;
  const __bf16* B_ = child ? Bc : Bp;
  const float* g2 = child ? cg2 : pg2;
  const float* be2 = child ? cbe2 : pbe2;
  const float* W2 = child ? cW2 : pW2;
  __bf16* outb = child ? fo : fi;
  int sbase = child ? ST_AGG : 0;
  float s2v[4], t2v[4];
#pragma unroll
  for (int ct = 0; ct < 4; ++ct) {
    int c = ct * 16 + q;
    float mu = stats[sbase + ST_SUM2 + c] * (1.f / NE);
    float var = stats[sbase + ST_SSQ2 + c] * (1.f / NE) - mu * mu;
    float s = g2[c] * rsqrtf(var + BN_EPS);
    s2v[ct] = s;
    t2v[ct] = be2[c] - mu * s;
  }
  bf16x8 wf[4][2];
#pragma unroll
  for (int ct = 0; ct < 4; ++ct)
#pragma unroll
    for (int kb = 0; kb < 2; ++kb) wf[ct][kb] = load_wfrag(W2, 64, kb, ct, lane);
  int w0 = child ? wgid - half : wgid;
  for (int n = w0; n < NN; n += half) {
    int p0 = off[n], p1 = off[n + 1];
    bf16x8 an0 = *(const bf16x8*)(A_ + (size_t)n * 64 + g * 8);
    bf16x8 an1 = *(const bf16x8*)(A_ + (size_t)n * 64 + 32 + g * 8);
    float oacc[4] = {0.f, 0.f, 0.f, 0.f};
    for (int pt = p0; pt < p1; pt += 16) {
      int m = p1 - pt;
      if (m > 16) m = 16;
      int pp = pt + q;
      int j = ij[q < m ? pp : p0].y;
      bf16x8 b0 = *(const bf16x8*)(B_ + (size_t)j * 64 + g * 8);
      bf16x8 b1 = *(const bf16x8*)(B_ + (size_t)j * 64 + 32 + g * 8);
      bf16x8 v0, v1;
#pragma unroll
      for (int jj = 0; jj < 8; ++jj) {
        v0[jj] = (__bf16)fmaxf((float)an0[jj] + (float)b0[jj], 0.f);
        v1[jj] = (__bf16)fmaxf((float)an1[jj] + (float)b1[jj], 0.f);
      }
#pragma unroll
      for (int ct = 0; ct < 4; ++ct) {
        floatx4 acc = {0.f, 0.f, 0.f, 0.f};
        acc = MFMA16(v0, wf[ct][0], acc);
        acc = MFMA16(v1, wf[ct][1], acc);
#pragma unroll
        for (int r = 0; r < 4; ++r)
          if (g * 4 + r < m) oacc[ct] += fmaxf(s2v[ct] * acc[r] + t2v[ct], 0.f);
      }
    }
#pragma unroll
    for (int ct = 0; ct < 4; ++ct) {
      oacc[ct] += __shfl_xor(oacc[ct], 16);
      oacc[ct] += __shfl_xor(oacc[ct], 32);
    }
    float val = (g == 0) ? oacc[0] : (g == 1) ? oacc[1] : (g == 2) ? oacc[2] : oacc[3];
    outb[(size_t)n * 64 + lane] = (__bf16)(dinv[n] * val);
  }
}

// KF: fused node update: upd = relu([x|fi|fo]@fcW + fcb)@fc2W + fc2b ; x += upd.
// Block 0 zeroes stats for the NEXT iteration.
__global__ void __launch_bounds__(256) k_node_update(
    float* __restrict__ x, const __bf16* __restrict__ fi, const __bf16* __restrict__ fo,
    const float* __restrict__ fcW, const float* __restrict__ fcb,
    const float* __restrict__ fc2W, const float* __restrict__ fc2b,
    float* __restrict__ stats) {
  const int lane = threadIdx.x & 63;
  const int wid = threadIdx.x >> 6;
  const int q = lane & 15, g = lane >> 4;
  __shared__ alignas(16) __bf16 v2[16 * 136];
  bf16x8 wf1[2][6];
#pragma unroll
  for (int c = 0; c < 2; ++c) {
    int ct = 2 * wid + c;
#pragma unroll
    for (int kb = 0; kb < 6; ++kb) wf1[c][kb] = load_wfrag(fcW, 128, kb, ct, lane);
  }
  bf16x8 wf2[4];
#pragma unroll
  for (int kb = 0; kb < 4; ++kb) wf2[kb] = load_wfrag(fc2W, 64, kb, wid, lane);
  float fcbv[2];
#pragma unroll
  for (int c = 0; c < 2; ++c) fcbv[c] = fcb[(2 * wid + c) * 16 + q];
  float fc2bv = fc2b[wid * 16 + q];

  for (int tile = blockIdx.x; tile < NN / 16; tile += gridDim.x) {
    int n = tile * 16 + q;
    const float4* xr0 = (const float4*)(x + (size_t)n * 64 + g * 8);
    const float4* xr1 = (const float4*)(x + (size_t)n * 64 + 32 + g * 8);
    float4 u0 = xr0[0], u1 = xr0[1], w0 = xr1[0], w1 = xr1[1];
    bf16x8 af[6];
#pragma unroll
    for (int j = 0; j < 4; ++j) {
      af[0][j] = (__bf16)(&u0.x)[j];
      af[0][4 + j] = (__bf16)(&u1.x)[j];
      af[1][j] = (__bf16)(&w0.x)[j];
      af[1][4 + j] = (__bf16)(&w1.x)[j];
    }
    af[2] = *(const bf16x8*)(fi + (size_t)n * 64 + g * 8);
    af[3] = *(const bf16x8*)(fi + (size_t)n * 64 + 32 + g * 8);
    af[4] = *(const bf16x8*)(fo + (size_t)n * 64 + g * 8);
    af[5] = *(const bf16x8*)(fo + (size_t)n * 64 + 32 + g * 8);
    floatx4 acc0 = {0.f, 0.f, 0.f, 0.f}, acc1 = {0.f, 0.f, 0.f, 0.f};
#pragma unroll
    for (int kb = 0; kb < 6; ++kb) {
      acc0 = MFMA16(af[kb], wf1[0][kb], acc0);
      acc1 = MFMA16(af[kb], wf1[1][kb], acc1);
    }
#pragma unroll
    for (int r = 0; r < 4; ++r) {
      int row = g * 4 + r;
      v2[row * 136 + (2 * wid) * 16 + q] = (__bf16)fmaxf(acc0[r] + fcbv[0], 0.f);
      v2[row * 136 + (2 * wid + 1) * 16 + q] = (__bf16)fmaxf(acc1[r] + fcbv[1], 0.f);
    }
    __syncthreads();
    floatx4 a2 = {0.f, 0.f, 0.f, 0.f};
#pragma unroll
    for (int kb = 0; kb < 4; ++kb) {
      bf16x8 af2 = *(const bf16x8*)&v2[q * 136 + kb * 32 + g * 8];
      a2 = MFMA16(af2, wf2[kb], a2);
    }
#pragma unroll
    for (int r = 0; r < 4; ++r) {
      int row = g * 4 + r;
      x[(size_t)(tile * 16 + row) * 64 + wid * 16 + q] += a2[r] + fc2bv;
    }
    __syncthreads();
  }
  if (blockIdx.x == 0)
    for (int t = threadIdx.x; t < 2 * ST_AGG; t += blockDim.x) stats[t] = 0.f;
}

// KG: out = x@convW + convb (f32 for accuracy margin).
__global__ void __launch_bounds__(256) k_conv(const float* __restrict__ x,
                                              const float* __restrict__ convW,
                                              const float* __restrict__ convb,
                                              float* __restrict__ out) {
  const int lane = threadIdx.x & 63;
  int wgid = (blockIdx.x * blockDim.x + threadIdx.x) >> 6;
  int nw = (gridDim.x * blockDim.x) >> 6;
  int half = wgid & 1;
  int col = half * 64 + lane;
  float wreg[64];
#pragma unroll
  for (int k = 0; k < 64; ++k) wreg[k] = convW[k * 128 + col];
  float bv = convb[col];
  for (int n = (wgid >> 1); n < NN; n += (nw >> 1)) {
    float xv = x[n * 64 + lane];
    float acc = bv;
#pragma unroll
    for (int k = 0; k < 64; ++k) acc += __shfl(xv, k) * wreg[k];
    out[(size_t)n * 128 + col] = acc;
  }
}

extern "C" void kernel_launch(void* const* d_in, const int* in_sizes, int n_in,
                              void* d_out, int out_size, void* d_ws, size_t ws_size,
                              hipStream_t stream) {
  const int* nodes = (const int*)d_in[0];
  const int* edges = (const int*)d_in[1];
  const int* src = edges;      // edges[0]
  const int* dst = edges + NE; // edges[1]
  const float* emb = (const float*)d_in[2];
  const float* pW1 = (const float*)d_in[3];
  const float* pg1 = (const float*)d_in[5];
  const float* pbe1 = (const float*)d_in[6];
  const float* pW2 = (const float*)d_in[7];
  const float* pg2 = (const float*)d_in[9];
  const float* pbe2 = (const float*)d_in[10];
  const float* cW1 = (const float*)d_in[11];
  const float* cg1 = (const float*)d_in[13];
  const float* cbe1 = (const float*)d_in[14];
  const float* cW2 = (const float*)d_in[15];
  const float* cg2 = (const float*)d_in[17];
  const float* cbe2 = (const float*)d_in[18];
  const float* fcW = (const float*)d_in[19];
  const float* fcb = (const float*)d_in[20];
  const float* fc2W = (const float*)d_in[21];
  const float* fc2b = (const float*)d_in[22];
  const float* convW = (const float*)d_in[23];
  const float* convb = (const float*)d_in[24];
  float* out = (float*)d_out;

  char* w = (char*)d_ws;
  auto alloc = [&](size_t bytes) {
    char* p = w;
    w += (bytes + 255) & ~(size_t)255;
    return p;
  };
  float* x = (float*)alloc((size_t)NN * 64 * 4);
  __bf16* Ap = (__bf16*)alloc((size_t)NN * 64 * 2);
  __bf16* Bp = (__bf16*)alloc((size_t)NN * 64 * 2);
  __bf16* Ac = (__bf16*)alloc((size_t)NN * 64 * 2);
  __bf16* Bc = (__bf16*)alloc((size_t)NN * 64 * 2);
  __bf16* fi = (__bf16*)alloc((size_t)NN * 64 * 2);
  __bf16* fo = (__bf16*)alloc((size_t)NN * 64 * 2);
  int2* ij_d = (int2*)alloc((size_t)NE * 8);
  int2* ij_s = (int2*)alloc((size_t)NE * 8);
  int* off_d = (int*)alloc((size_t)(NN + 1) * 4);
  int* off_s = (int*)alloc((size_t)(NN + 1) * 4);
  int* cnt_d = (int*)alloc((size_t)NN * 4);
  int* cnt_s = (int*)alloc((size_t)NN * 4);
  float* dinv_d = (float*)alloc((size_t)NN * 4);
  float* dinv_s = (float*)alloc((size_t)NN * 4);
  float* stats = (float*)alloc(2 * ST_AGG * 4);
  int* btot = (int*)alloc(2 * SCAN_NB * 4);

  k_setup<<<1024, 256, 0, stream>>>(nodes, emb, x, cnt_d, cnt_s);
  k_hist<<<1024, 256, 0, stream>>>(src, dst, cnt_d, cnt_s);
  k_scan1<<<dim3(SCAN_NB, 2), SCAN_T, 0, stream>>>(cnt_d, cnt_s, off_d, off_s, btot);
  k_scan2<<<1, SCAN_T, 0, stream>>>(btot);
  k_scan3<<<dim3(SCAN_NB, 2), SCAN_T, 0, stream>>>(cnt_d, cnt_s, off_d, off_s, btot,
                                                   dinv_d, dinv_s);
  k_fill_gather<<<FILL_B, FILL_T, 0, stream>>>(src, dst, off_d, off_s, ij_d, ij_s, stats);

  for (int it = 0; it < 2; ++it) {
    k_node_xform<<<dim3(784, 2), 256, 0, stream>>>(x, pW1, cW1, Ap, Bp, Ac, Bc,
                                                   cnt_d, cnt_s, stats);
    k_crossp<<<2048, 256, 0, stream>>>(ij_d, Ap, Bp, Ac, Bc, stats);
    k_prescale<<<1024, 256, 0, stream>>>(Ap, Bp, Ac, Bc, pg1, pbe1, cg1, cbe1, stats);
    k_bn2p<<<4096, 256, 0, stream>>>(ij_d, Ap, Bp, Ac, Bc, pW2, cW2, stats);
    k_scatter_both<<<4096, 256, 0, stream>>>(off_d, dinv_d, ij_d, off_s, dinv_s, ij_s,
                                             Ap, Bp, Ac, Bc, pg2, pbe2, cg2, cbe2,
                                             pW2, cW2, stats, fi, fo);
    k_node_update<<<3125, 256, 0, stream>>>(x, fi, fo, fcW, fcb, fc2W, fc2b, stats);
  }
  k_conv<<<2048, 256, 0, stream>>>(x, convW, convb, out);
}